// Round 13
// baseline (115.972 us; speedup 1.0000x reference)
//
#include <hip/hip_runtime.h>
#include <math.h>

#define B_  8
#define N_  128
#define T_  256
#define L_  32
#define H_  128
#define TT_ 224   // T - L

typedef float f2    __attribute__((ext_vector_type(2)));
typedef float f4    __attribute__((ext_vector_type(4)));
typedef float f32x4 __attribute__((ext_vector_type(4)));
typedef short bf16x8 __attribute__((ext_vector_type(8)));

#define L2E_  1.4426950408889634f
#define L2E2_ 2.8853900817779268f

__device__ __forceinline__ unsigned pk2bf(float a, float b) {   // RNE bf16 pack
    unsigned ua = __float_as_uint(a), ub = __float_as_uint(b);
    ua = (ua + 0x7FFFu + ((ua >> 16) & 1u)) >> 16;
    ub = (ub + 0x7FFFu + ((ub >> 16) & 1u)) >> 16;
    return ua | (ub << 16);
}
__device__ __forceinline__ float aexp2(float x) {
    float r; asm("v_exp_f32 %0, %1" : "=v"(r) : "v"(x)); return r;
}
__device__ __forceinline__ float aexp2n(float x) {
    float r; asm("v_exp_f32 %0, -%1" : "=v"(r) : "v"(x)); return r;
}
__device__ __forceinline__ float arcp(float x) {
    return __builtin_amdgcn_rcpf(x);
}

// activation: gates (bias already added, pre-scaled by log2e factors) -> hh
//   A=(1+e1)(e2+1), B=1+e3, R=rcp(A*B), t=em*R (em=e2-1),
//   c=t*B (= sig(gi)tanh(gg)), hh=t*Q(c^2) (= sig(go)*poly7tanh(c)).
__device__ __forceinline__ f32x4 lstm_act(f32x4 gi, f32x4 gg, f32x4 go) {
    f32x4 e1, e2, e3;
    #pragma unroll
    for (int r = 0; r < 4; ++r) {
        e1[r] = aexp2n(gi[r]);              // e^-gi
        e2[r] = aexp2(gg[r]);               // e^2gg
        e3[r] = aexp2n(go[r]);              // e^-go
    }
    const f32x4 A  = (1.f + e1) * (e2 + 1.f);
    const f32x4 Bv = 1.f + e3;
    const f32x4 AB = A * Bv;
    f32x4 R;
    #pragma unroll
    for (int r = 0; r < 4; ++r) R[r] = arcp(AB[r]);
    const f32x4 em = e2 - 1.f;
    const f32x4 t  = em * R;
    const f32x4 c  = t * Bv;                // sig(gi)*tanh(gg)
    const f32x4 c2 = c * c;
    f32x4 Q = c2 * -0.027698f + 0.120833f;
    Q = c2 * Q - 0.331541f;
    Q = c2 * Q + 1.0f;
    return t * Q;                           // sig(go)*tanh(c)
}

// ---------------------------------------------------------------------------
// R13 = R12 with the LATENCY structure attacked (5 falsified throughput
// levers: occupancy R5, VGPR-budget R6, W-traffic R7, writes R8, DS-ops R12;
// counters pinned at VALUBusy~41/Occ~28 -> latency-bound; VGPR=64 shows the
// compiler starved the scheduler of registers chasing unrealizable 8 w/EU):
//   - amdgpu_waves_per_eu(4,4): pin the TRUE residency (16 waves/CU), so
//     the allocator may use the full 128-VGPR budget for scheduling,
//   - both batches INTERLEAVED per tile: two independent ~30-reg dependency
//     chains adjacent in program order -> scheduler ping-pongs chains
//     instead of stalling on one.
// HARD CONSTRAINT (R2/R3/R9, 3/3 NaN): bias NEVER via MFMA C-operand;
// explicit f32x4 add after MFMA (C = zero4).
// Numerics identical to R12 (same frag builds, activation, reductions).
// ---------------------------------------------------------------------------
__global__ __launch_bounds__(512, 4)
__attribute__((amdgpu_waves_per_eu(4, 4)))
void k_main(const float* __restrict__ x,
            const float* __restrict__ W_ih,
            const float* __restrict__ b_ih, const float* __restrict__ b_hh,
            const float* __restrict__ W_fc, const float* __restrict__ b_fc,
            float* __restrict__ G, float* __restrict__ xhat) {
    const int n   = blockIdx.x;
    const int y   = blockIdx.y;        // batch pair
    const int b0  = 2 * y;
    const int tid = threadIdx.x;
    const int w    = tid >> 6;    // wave 0..7  == ht
    const int lane = tid & 63;
    const int col  = lane & 15;   // MFMA n index -> t_local
    const int quad = lane >> 4;   // MFMA k-group / row-group

    __shared__ __attribute__((aligned(16))) float xs[2][260];
    __shared__ __attribute__((aligned(16))) unsigned xeo[2][2][128];
    __shared__ __attribute__((aligned(16))) float xr[2][TT_];
    __shared__ uint4 xA[2 * 14 * 64];                  // 28 KB frag table
    __shared__ __attribute__((aligned(16))) float xh_part[2][8][TT_];
    __shared__ __attribute__((aligned(16))) float hd_loc[2][H_];
    __shared__ float red[8];
    __shared__ f4 ws4[32];             // wsum, 16B-aligned
    __shared__ float bp[2];
    __shared__ float bs_s;

    // wsum partials overlay the xA region (wpart live phases A-B; xA built
    // in phase C after the barrier ending wpart's last read). R5-proven.
    f4* wpart = (f4*)xA;

    // ---- phase A: all global reads (W-side paid once for both batches) ----
    union { uint4 u; bf16x8 v; } bfr[3];
    f32x4 biaR[3];
    {
        const int ht = w;
        const int hb = ht * 16 + quad * 4;   // h-base of this lane's 4 rows
        #pragma unroll
        for (int g = 0; g < 3; ++g) {
            const int r  = g * 128 + ht * 16 + col;
            const int sr = r + (r >= 128 ? 128 : 0);
            const float sc = (g == 1) ? L2E2_ : L2E_;
            const f4* src = (const f4*)(W_ih + (size_t)n * 512 * L_ +
                                        (size_t)sr * L_ + quad * 8);
            f4 v0 = src[0] * sc, v1 = src[1] * sc;
            bfr[g].u.x = pk2bf(v0.x, v0.y);
            bfr[g].u.y = pk2bf(v0.z, v0.w);
            bfr[g].u.z = pk2bf(v1.x, v1.y);
            bfr[g].u.w = pk2bf(v1.z, v1.w);
            const int sg = (g == 0) ? 0 : (g == 1 ? 256 : 384);
            const f4 bi = *(const f4*)&b_ih[(size_t)n * 512 + sg + hb];
            const f4 bh = *(const f4*)&b_hh[(size_t)n * 512 + sg + hb];
            const f4 bs = (bi + bh) * sc;
            biaR[g][0] = bs.x; biaR[g][1] = bs.y;
            biaR[g][2] = bs.z; biaR[g][3] = bs.w;
        }
    }
    {   // wsum partials: thread (jg=tid>>5 in 0..15, h4=tid&31) sums 8 j
        const int h4 = tid & 31, jg = tid >> 5;
        const f4* Wf = (const f4*)(W_fc + (size_t)n * N_ * H_) +
                       (size_t)jg * 8 * 32 + h4;
        f4 s = {0.f, 0.f, 0.f, 0.f};
        #pragma unroll
        for (int j = 0; j < 8; ++j) s += Wf[j * 32];
        wpart[jg * 32 + h4] = s;
    }
    if (tid < 128) {   // bsum partials
        float bv = b_fc[n * N_ + tid];
        #pragma unroll
        for (int off = 32; off > 0; off >>= 1) bv += __shfl_down(bv, off, 64);
        if ((tid & 63) == 0) bp[tid >> 6] = bv;
    }
    // stage x for both batches
    if (tid < 256) xs[0][tid] = x[((size_t)b0 * N_ + n) * T_ + tid];
    else           xs[1][tid - 256] = x[((size_t)(b0 + 1) * N_ + n) * T_ + (tid - 256)];
    if (tid < 4) { xs[0][256 + tid] = 0.f; xs[1][256 + tid] = 0.f; }
    __syncthreads();

    // ---- phase B: derived from staged data ----
    if (tid < TT_)                          xr[0][tid]       = 1.0f / xs[0][L_ + tid];
    else if (tid >= 256 && tid < 256 + TT_) xr[1][tid - 256] = 1.0f / xs[1][L_ + tid - 256];
    if (tid < 128) {
        xeo[0][0][tid] = pk2bf(xs[0][2 * tid],     xs[0][2 * tid + 1]);
        xeo[0][1][tid] = pk2bf(xs[0][2 * tid + 1], xs[0][2 * tid + 2]);
    } else if (tid >= 256 && tid < 384) {
        const int t2 = tid - 256;
        xeo[1][0][t2] = pk2bf(xs[1][2 * t2],     xs[1][2 * t2 + 1]);
        xeo[1][1][t2] = pk2bf(xs[1][2 * t2 + 1], xs[1][2 * t2 + 2]);
    }
    if (tid < 32) {   // wsum reduce across 16 jg partials
        f4 s = wpart[tid];
        #pragma unroll
        for (int jg = 1; jg < 16; ++jg) s += wpart[jg * 32 + tid];
        ws4[tid] = s;
    }
    if (tid == 0) bs_s = bp[0] + bp[1];
    __syncthreads();          // wpart's last read done; xA region now free

    // ---- phase C: build per-lane frag table for BOTH batches ----
    for (int e = tid; e < 2 * 14 * 64; e += 512) {
        const int bb = e / 896;
        const int r  = e - bb * 896;
        const int tt = r >> 6, ln = r & 63;
        const int s  = tt * 16 + (ln & 15) + (ln >> 4) * 8;
        const int p  = s & 1, base = s >> 1;
        uint4 v;
        v.x = xeo[bb][p][base + 0]; v.y = xeo[bb][p][base + 1];
        v.z = xeo[bb][p][base + 2]; v.w = xeo[bb][p][base + 3];
        xA[e] = v;
    }
    __syncthreads();

    // wsum for this lane's 4 output rows
    const f4 wshF = ws4[(w * 16 + quad * 4) >> 2];
    const float bsum_n = bs_s;

    const f32x4 zero4 = {0.f, 0.f, 0.f, 0.f};

    // ---- main: both batches INTERLEAVED per tile (dual dep-chains) ----
    f32x4 hdacc0 = {0.f, 0.f, 0.f, 0.f};
    f32x4 hdacc1 = {0.f, 0.f, 0.f, 0.f};
    #pragma unroll
    for (int ttile = 0; ttile < 14; ++ttile) {
        union { uint4 u; bf16x8 v; } af0, af1;
        af0.u = xA[ttile * 64 + lane];              // batch 0 frag
        af1.u = xA[(14 + ttile) * 64 + lane];       // batch 1 frag
        const float xrt0 = xr[0][ttile * 16 + col];
        const float xrt1 = xr[1][ttile * 16 + col];

        // swapped operands: A = W-frag (m=h_sub), B = x-frag (n=t), C = 0
        f32x4 gi0 = __builtin_amdgcn_mfma_f32_16x16x32_bf16(bfr[0].v, af0.v, zero4, 0, 0, 0);
        f32x4 gg0 = __builtin_amdgcn_mfma_f32_16x16x32_bf16(bfr[1].v, af0.v, zero4, 0, 0, 0);
        f32x4 go0 = __builtin_amdgcn_mfma_f32_16x16x32_bf16(bfr[2].v, af0.v, zero4, 0, 0, 0);
        f32x4 gi1 = __builtin_amdgcn_mfma_f32_16x16x32_bf16(bfr[0].v, af1.v, zero4, 0, 0, 0);
        f32x4 gg1 = __builtin_amdgcn_mfma_f32_16x16x32_bf16(bfr[1].v, af1.v, zero4, 0, 0, 0);
        f32x4 go1 = __builtin_amdgcn_mfma_f32_16x16x32_bf16(bfr[2].v, af1.v, zero4, 0, 0, 0);

        // explicit bias add (NEVER via the C operand) + activation
        const f32x4 hh0 = lstm_act(gi0 + biaR[0], gg0 + biaR[1], go0 + biaR[2]);
        const f32x4 hh1 = lstm_act(gi1 + biaR[0], gg1 + biaR[1], go1 + biaR[2]);

        hdacc0 += hh0 * xrt0;                   // hd partials (t-sum in-lane)
        hdacc1 += hh1 * xrt1;

        float xsum0 = fmaf(hh0[0], wshF.x, fmaf(hh0[1], wshF.y,
                      fmaf(hh0[2], wshF.z, fmaf(hh0[3], wshF.w, 0.f))));
        float xsum1 = fmaf(hh1[0], wshF.x, fmaf(hh1[1], wshF.y,
                      fmaf(hh1[2], wshF.z, fmaf(hh1[3], wshF.w, 0.f))));
        // X_hat partials for t = ttile*16+col: sum over quads
        xsum0 += __shfl_xor(xsum0, 16, 64);
        xsum1 += __shfl_xor(xsum1, 16, 64);
        xsum0 += __shfl_xor(xsum0, 32, 64);
        xsum1 += __shfl_xor(xsum1, 32, 64);
        if (lane < 16) {
            xh_part[0][w][ttile * 16 + lane] = xsum0;
            xh_part[1][w][ttile * 16 + lane] = xsum1;
        }
    }

    // ---- Hd -> LDS: cross-col reduce (both batches) ----
    #pragma unroll
    for (int r = 0; r < 4; ++r) {
        float v0 = hdacc0[r], v1 = hdacc1[r];
        v0 += __shfl_xor(v0, 1, 64);  v1 += __shfl_xor(v1, 1, 64);
        v0 += __shfl_xor(v0, 2, 64);  v1 += __shfl_xor(v1, 2, 64);
        v0 += __shfl_xor(v0, 4, 64);  v1 += __shfl_xor(v1, 4, 64);
        v0 += __shfl_xor(v0, 8, 64);  v1 += __shfl_xor(v1, 8, 64);
        if (col == 0) {
            hd_loc[0][w * 16 + quad * 4 + r] = v0;
            hd_loc[1][w * 16 + quad * 4 + r] = v1;
        }
    }

    // ---- Dinv partials: waves 0-3 -> batch0, waves 4-7 -> batch1 ----
    {
        const int bb = w >> 2;
        const int t2 = tid - bb * 256;
        float dv = (t2 < TT_) ? xr[bb][t2] : 0.f;
        #pragma unroll
        for (int off = 32; off > 0; off >>= 1) dv += __shfl_down(dv, off, 64);
        if (lane == 0) red[w] = dv;
    }
    __syncthreads();

    // ---- X_hat writeout (both batches) ----
    {
        const int bb = tid >> 8;
        const int tt = tid & 255;
        if (tt < TT_) {
            const float v = (xh_part[bb][0][tt] + xh_part[bb][1][tt]) +
                            (xh_part[bb][2][tt] + xh_part[bb][3][tt]) +
                            (xh_part[bb][4][tt] + xh_part[bb][5][tt]) +
                            (xh_part[bb][6][tt] + xh_part[bb][7][tt]);
            xhat[((size_t)(b0 + bb) * TT_ + tt) * N_ + n] = v + bsum_n + 1e-6f;
        }
    }

    // ---- fused G epilogue: W_fc read once, used for both batches ----
    {
        const float dinv0 = (red[0] + red[1]) + (red[2] + red[3]);
        const float dinv1 = (red[4] + red[5]) + (red[6] + red[7]);
        const int j   = tid >> 2;
        const int qtr = tid & 3;
        const f4* Wf = (const f4*)(W_fc + ((size_t)n * N_ + j) * H_ + qtr * 32);
        float s0 = 0.f, s1 = 0.f;
        #pragma unroll
        for (int q = 0; q < 8; ++q) {
            const f4 wv = Wf[q];
            const int hb = qtr * 32 + q * 4;
            s0 = fmaf(wv.x, hd_loc[0][hb + 0],
                 fmaf(wv.y, hd_loc[0][hb + 1],
                 fmaf(wv.z, hd_loc[0][hb + 2],
                 fmaf(wv.w, hd_loc[0][hb + 3], s0))));
            s1 = fmaf(wv.x, hd_loc[1][hb + 0],
                 fmaf(wv.y, hd_loc[1][hb + 1],
                 fmaf(wv.z, hd_loc[1][hb + 2],
                 fmaf(wv.w, hd_loc[1][hb + 3], s1))));
        }
        s0 += __shfl_xor(s0, 1, 64);
        s0 += __shfl_xor(s0, 2, 64);
        s1 += __shfl_xor(s1, 1, 64);
        s1 += __shfl_xor(s1, 2, 64);
        if (qtr == 0) {
            const float bj = b_fc[n * N_ + j];
            G[(size_t)b0 * N_ * N_ + (size_t)j * N_ + n] =
                (s0 + bj * dinv0) * (1.0f / 224.0f);
            G[(size_t)(b0 + 1) * N_ * N_ + (size_t)j * N_ + n] =
                (s1 + bj * dinv1) * (1.0f / 224.0f);
        }
    }
}

// ---------------------------------------------------------------------------
extern "C" void kernel_launch(void* const* d_in, const int* in_sizes, int n_in,
                              void* d_out, int out_size, void* d_ws, size_t ws_size,
                              hipStream_t stream) {
    const float* x    = (const float*)d_in[0];
    const float* W_ih = (const float*)d_in[1];
    const float* b_ih = (const float*)d_in[2];
    const float* b_hh = (const float*)d_in[3];
    const float* W_fc = (const float*)d_in[4];
    const float* b_fc = (const float*)d_in[5];

    float* G    = (float*)d_out;                        // B*N*N = 131072
    float* xhat = (float*)d_out + (size_t)B_ * N_ * N_; // B*TT*N = 229376

    (void)d_ws; (void)ws_size;   // workspace unused

    k_main<<<dim3(N_, B_ / 2), dim3(512), 0, stream>>>(x, W_ih, b_ih, b_hh,
                                                       W_fc, b_fc, G, xhat);
}

// Round 14
// 107.514 us; speedup vs baseline: 1.0787x; 1.0787x over previous
//
#include <hip/hip_runtime.h>
#include <math.h>

#define B_  8
#define N_  128
#define T_  256
#define L_  32
#define H_  128
#define TT_ 224   // T - L

typedef float f2    __attribute__((ext_vector_type(2)));
typedef float f4    __attribute__((ext_vector_type(4)));
typedef float f32x4 __attribute__((ext_vector_type(4)));
typedef short bf16x8 __attribute__((ext_vector_type(8)));

#define L2E_  1.4426950408889634f
#define L2E2_ 2.8853900817779268f

__device__ __forceinline__ unsigned pk2bf(float a, float b) {   // RNE bf16 pack
    unsigned ua = __float_as_uint(a), ub = __float_as_uint(b);
    ua = (ua + 0x7FFFu + ((ua >> 16) & 1u)) >> 16;
    ub = (ub + 0x7FFFu + ((ub >> 16) & 1u)) >> 16;
    return ua | (ub << 16);
}
__device__ __forceinline__ float aexp2(float x) {
    float r; asm("v_exp_f32 %0, %1" : "=v"(r) : "v"(x)); return r;
}
__device__ __forceinline__ float aexp2n(float x) {
    float r; asm("v_exp_f32 %0, -%1" : "=v"(r) : "v"(x)); return r;
}
__device__ __forceinline__ float arcp(float x) {
    return __builtin_amdgcn_rcpf(x);
}

// activation on an f2 pair (bias already added, pre-scaled by log2e):
//   A=(1+e1)(e2+1), B=1+e3, R=rcp(A*B), t=em*R (em=e2-1),
//   c=t*B (= sig(gi)tanh(gg)), hh=t*Q(c^2) (= sig(go)*poly7tanh(c)).
// f2 width: ~15 live regs per chain (vs ~30 for f32x4) -> two independent
// chains fit the 64-VGPR wall; f2 vector ops invite v_pk_*_f32 packing.
__device__ __forceinline__ f2 lstm_act2(f2 gi, f2 gg, f2 go) {
    f2 e1 = {aexp2n(gi.x), aexp2n(gi.y)};   // e^-gi
    f2 e2 = {aexp2(gg.x),  aexp2(gg.y)};    // e^2gg
    f2 e3 = {aexp2n(go.x), aexp2n(go.y)};   // e^-go
    const f2 A  = (1.f + e1) * (e2 + 1.f);
    const f2 Bv = 1.f + e3;
    const f2 AB = A * Bv;
    f2 R = {arcp(AB.x), arcp(AB.y)};
    const f2 em = e2 - 1.f;
    const f2 t  = em * R;
    const f2 c  = t * Bv;                   // sig(gi)*tanh(gg)
    const f2 c2 = c * c;
    f2 Q = c2 * -0.027698f + 0.120833f;
    Q = c2 * Q - 0.331541f;
    Q = c2 * Q + 1.0f;
    return t * Q;                           // sig(go)*tanh(c)
}

// ---------------------------------------------------------------------------
// R14 = R12 (best passing structure: xA table, batch-paired, sequential bb
// loop, no waves_per_eu) with the activation split into TWO f2 half-chains
// per tile. R13's spill (VGPR pinned 64, +96 MB scratch traffic) proved the
// 64-VGPR wall blocks f32x4-width ILP; f2 chains (~15 regs each) provide the
// same dual-chain overlap IN budget, and invite v_pk_*_f32 dual-issue.
// Numerics element-identical to R12 (same ops, same per-element order).
// HARD CONSTRAINT (R2/R3/R9, 3/3 NaN): bias NEVER via MFMA C-operand;
// explicit add after MFMA (C = zero4).
// ---------------------------------------------------------------------------
__global__ __launch_bounds__(512, 4)
void k_main(const float* __restrict__ x,
            const float* __restrict__ W_ih,
            const float* __restrict__ b_ih, const float* __restrict__ b_hh,
            const float* __restrict__ W_fc, const float* __restrict__ b_fc,
            float* __restrict__ G, float* __restrict__ xhat) {
    const int n   = blockIdx.x;
    const int y   = blockIdx.y;        // batch pair
    const int b0  = 2 * y;
    const int tid = threadIdx.x;
    const int w    = tid >> 6;    // wave 0..7  == ht
    const int lane = tid & 63;
    const int col  = lane & 15;   // MFMA n index -> t_local
    const int quad = lane >> 4;   // MFMA k-group / row-group

    __shared__ __attribute__((aligned(16))) float xs[2][260];
    __shared__ __attribute__((aligned(16))) unsigned xeo[2][2][128];
    __shared__ __attribute__((aligned(16))) float xr[2][TT_];
    __shared__ uint4 xA[2 * 14 * 64];                  // 28 KB frag table
    __shared__ __attribute__((aligned(16))) float xh_part[2][8][TT_];
    __shared__ __attribute__((aligned(16))) float hd_loc[2][H_];
    __shared__ float red[8];
    __shared__ f4 ws4[32];             // wsum, 16B-aligned
    __shared__ float bp[2];
    __shared__ float bs_s;

    // wsum partials overlay the xA region (wpart live phases A-B; xA built
    // in phase C after the barrier ending wpart's last read). R5-proven.
    f4* wpart = (f4*)xA;

    // ---- phase A: all global reads (W-side paid once for both batches) ----
    union { uint4 u; bf16x8 v; } bfr[3];
    f32x4 biaR[3];
    {
        const int ht = w;
        const int hb = ht * 16 + quad * 4;   // h-base of this lane's 4 rows
        #pragma unroll
        for (int g = 0; g < 3; ++g) {
            const int r  = g * 128 + ht * 16 + col;
            const int sr = r + (r >= 128 ? 128 : 0);
            const float sc = (g == 1) ? L2E2_ : L2E_;
            const f4* src = (const f4*)(W_ih + (size_t)n * 512 * L_ +
                                        (size_t)sr * L_ + quad * 8);
            f4 v0 = src[0] * sc, v1 = src[1] * sc;
            bfr[g].u.x = pk2bf(v0.x, v0.y);
            bfr[g].u.y = pk2bf(v0.z, v0.w);
            bfr[g].u.z = pk2bf(v1.x, v1.y);
            bfr[g].u.w = pk2bf(v1.z, v1.w);
            const int sg = (g == 0) ? 0 : (g == 1 ? 256 : 384);
            const f4 bi = *(const f4*)&b_ih[(size_t)n * 512 + sg + hb];
            const f4 bh = *(const f4*)&b_hh[(size_t)n * 512 + sg + hb];
            const f4 bs = (bi + bh) * sc;
            biaR[g][0] = bs.x; biaR[g][1] = bs.y;
            biaR[g][2] = bs.z; biaR[g][3] = bs.w;
        }
    }
    {   // wsum partials: thread (jg=tid>>5 in 0..15, h4=tid&31) sums 8 j
        const int h4 = tid & 31, jg = tid >> 5;
        const f4* Wf = (const f4*)(W_fc + (size_t)n * N_ * H_) +
                       (size_t)jg * 8 * 32 + h4;
        f4 s = {0.f, 0.f, 0.f, 0.f};
        #pragma unroll
        for (int j = 0; j < 8; ++j) s += Wf[j * 32];
        wpart[jg * 32 + h4] = s;
    }
    if (tid < 128) {   // bsum partials
        float bv = b_fc[n * N_ + tid];
        #pragma unroll
        for (int off = 32; off > 0; off >>= 1) bv += __shfl_down(bv, off, 64);
        if ((tid & 63) == 0) bp[tid >> 6] = bv;
    }
    // stage x for both batches
    if (tid < 256) xs[0][tid] = x[((size_t)b0 * N_ + n) * T_ + tid];
    else           xs[1][tid - 256] = x[((size_t)(b0 + 1) * N_ + n) * T_ + (tid - 256)];
    if (tid < 4) { xs[0][256 + tid] = 0.f; xs[1][256 + tid] = 0.f; }
    __syncthreads();

    // ---- phase B: derived from staged data ----
    if (tid < TT_)                          xr[0][tid]       = 1.0f / xs[0][L_ + tid];
    else if (tid >= 256 && tid < 256 + TT_) xr[1][tid - 256] = 1.0f / xs[1][L_ + tid - 256];
    if (tid < 128) {
        xeo[0][0][tid] = pk2bf(xs[0][2 * tid],     xs[0][2 * tid + 1]);
        xeo[0][1][tid] = pk2bf(xs[0][2 * tid + 1], xs[0][2 * tid + 2]);
    } else if (tid >= 256 && tid < 384) {
        const int t2 = tid - 256;
        xeo[1][0][t2] = pk2bf(xs[1][2 * t2],     xs[1][2 * t2 + 1]);
        xeo[1][1][t2] = pk2bf(xs[1][2 * t2 + 1], xs[1][2 * t2 + 2]);
    }
    if (tid < 32) {   // wsum reduce across 16 jg partials
        f4 s = wpart[tid];
        #pragma unroll
        for (int jg = 1; jg < 16; ++jg) s += wpart[jg * 32 + tid];
        ws4[tid] = s;
    }
    if (tid == 0) bs_s = bp[0] + bp[1];
    __syncthreads();          // wpart's last read done; xA region now free

    // ---- phase C: build per-lane frag table for BOTH batches ----
    for (int e = tid; e < 2 * 14 * 64; e += 512) {
        const int bb = e / 896;
        const int r  = e - bb * 896;
        const int tt = r >> 6, ln = r & 63;
        const int s  = tt * 16 + (ln & 15) + (ln >> 4) * 8;
        const int p  = s & 1, base = s >> 1;
        uint4 v;
        v.x = xeo[bb][p][base + 0]; v.y = xeo[bb][p][base + 1];
        v.z = xeo[bb][p][base + 2]; v.w = xeo[bb][p][base + 3];
        xA[e] = v;
    }
    __syncthreads();

    // wsum for this lane's 4 output rows
    const f4 wshF = ws4[(w * 16 + quad * 4) >> 2];
    const float bsum_n = bs_s;

    const f32x4 zero4 = {0.f, 0.f, 0.f, 0.f};

    // ---- main: both batches, W state reused; f2 dual-chain activation ----
    #pragma unroll
    for (int bb = 0; bb < 2; ++bb) {
        f2 hdA = {0.f, 0.f}, hdB = {0.f, 0.f};
        #pragma unroll
        for (int ttile = 0; ttile < 14; ++ttile) {
            union { uint4 u; bf16x8 v; } af;   // one clean ds_read_b128
            af.u = xA[(bb * 14 + ttile) * 64 + lane];
            const float xrt = xr[bb][ttile * 16 + col];

            // swapped operands: A = W-frag (m=h_sub), B = x-frag (n=t), C = 0
            f32x4 gi = __builtin_amdgcn_mfma_f32_16x16x32_bf16(bfr[0].v, af.v, zero4, 0, 0, 0);
            f32x4 gg = __builtin_amdgcn_mfma_f32_16x16x32_bf16(bfr[1].v, af.v, zero4, 0, 0, 0);
            f32x4 go = __builtin_amdgcn_mfma_f32_16x16x32_bf16(bfr[2].v, af.v, zero4, 0, 0, 0);
            gi += biaR[0];                      // explicit per-row bias add
            gg += biaR[1];                      // (NEVER via the C operand)
            go += biaR[2];

            // two independent f2 half-chains (regs 0,1 and 2,3)
            const f2 hhA = lstm_act2((f2){gi[0], gi[1]}, (f2){gg[0], gg[1]},
                                     (f2){go[0], go[1]});
            const f2 hhB = lstm_act2((f2){gi[2], gi[3]}, (f2){gg[2], gg[3]},
                                     (f2){go[2], go[3]});

            hdA += hhA * xrt;                   // hd partials (t-sum in-lane)
            hdB += hhB * xrt;
            // same fmaf order as R12: hh0,hh1,hh2,hh3 innermost-to-outermost
            float xsum = fmaf(hhA.x, wshF.x,
                         fmaf(hhA.y, wshF.y,
                         fmaf(hhB.x, wshF.z,
                         fmaf(hhB.y, wshF.w, 0.f))));
            // X_hat partial for t = ttile*16+col: sum over quads
            xsum += __shfl_xor(xsum, 16, 64);
            xsum += __shfl_xor(xsum, 32, 64);
            if (lane < 16) xh_part[bb][w][ttile * 16 + lane] = xsum;
        }
        // Hd -> LDS: cross-col reduce (per batch)
        #pragma unroll
        for (int r = 0; r < 4; ++r) {
            float v = (r < 2) ? hdA[r] : hdB[r - 2];
            v += __shfl_xor(v, 1, 64);
            v += __shfl_xor(v, 2, 64);
            v += __shfl_xor(v, 4, 64);
            v += __shfl_xor(v, 8, 64);
            if (col == 0) hd_loc[bb][w * 16 + quad * 4 + r] = v;
        }
    }

    // ---- Dinv partials: waves 0-3 -> batch0, waves 4-7 -> batch1 ----
    {
        const int bb = w >> 2;
        const int t2 = tid - bb * 256;
        float dv = (t2 < TT_) ? xr[bb][t2] : 0.f;
        #pragma unroll
        for (int off = 32; off > 0; off >>= 1) dv += __shfl_down(dv, off, 64);
        if (lane == 0) red[w] = dv;
    }
    __syncthreads();

    // ---- X_hat writeout (both batches) ----
    {
        const int bb = tid >> 8;
        const int tt = tid & 255;
        if (tt < TT_) {
            const float v = (xh_part[bb][0][tt] + xh_part[bb][1][tt]) +
                            (xh_part[bb][2][tt] + xh_part[bb][3][tt]) +
                            (xh_part[bb][4][tt] + xh_part[bb][5][tt]) +
                            (xh_part[bb][6][tt] + xh_part[bb][7][tt]);
            xhat[((size_t)(b0 + bb) * TT_ + tt) * N_ + n] = v + bsum_n + 1e-6f;
        }
    }

    // ---- fused G epilogue: W_fc read once, used for both batches ----
    {
        const float dinv0 = (red[0] + red[1]) + (red[2] + red[3]);
        const float dinv1 = (red[4] + red[5]) + (red[6] + red[7]);
        const int j   = tid >> 2;
        const int qtr = tid & 3;
        const f4* Wf = (const f4*)(W_fc + ((size_t)n * N_ + j) * H_ + qtr * 32);
        float s0 = 0.f, s1 = 0.f;
        #pragma unroll
        for (int q = 0; q < 8; ++q) {
            const f4 wv = Wf[q];
            const int hb = qtr * 32 + q * 4;
            s0 = fmaf(wv.x, hd_loc[0][hb + 0],
                 fmaf(wv.y, hd_loc[0][hb + 1],
                 fmaf(wv.z, hd_loc[0][hb + 2],
                 fmaf(wv.w, hd_loc[0][hb + 3], s0))));
            s1 = fmaf(wv.x, hd_loc[1][hb + 0],
                 fmaf(wv.y, hd_loc[1][hb + 1],
                 fmaf(wv.z, hd_loc[1][hb + 2],
                 fmaf(wv.w, hd_loc[1][hb + 3], s1))));
        }
        s0 += __shfl_xor(s0, 1, 64);
        s0 += __shfl_xor(s0, 2, 64);
        s1 += __shfl_xor(s1, 1, 64);
        s1 += __shfl_xor(s1, 2, 64);
        if (qtr == 0) {
            const float bj = b_fc[n * N_ + j];
            G[(size_t)b0 * N_ * N_ + (size_t)j * N_ + n] =
                (s0 + bj * dinv0) * (1.0f / 224.0f);
            G[(size_t)(b0 + 1) * N_ * N_ + (size_t)j * N_ + n] =
                (s1 + bj * dinv1) * (1.0f / 224.0f);
        }
    }
}

// ---------------------------------------------------------------------------
extern "C" void kernel_launch(void* const* d_in, const int* in_sizes, int n_in,
                              void* d_out, int out_size, void* d_ws, size_t ws_size,
                              hipStream_t stream) {
    const float* x    = (const float*)d_in[0];
    const float* W_ih = (const float*)d_in[1];
    const float* b_ih = (const float*)d_in[2];
    const float* b_hh = (const float*)d_in[3];
    const float* W_fc = (const float*)d_in[4];
    const float* b_fc = (const float*)d_in[5];

    float* G    = (float*)d_out;                        // B*N*N = 131072
    float* xhat = (float*)d_out + (size_t)B_ * N_ * N_; // B*TT*N = 229376

    (void)d_ws; (void)ws_size;   // workspace unused

    k_main<<<dim3(N_, B_ / 2), dim3(512), 0, stream>>>(x, W_ih, b_ih, b_hh,
                                                       W_fc, b_fc, G, xhat);
}

// Round 15
// 104.345 us; speedup vs baseline: 1.1114x; 1.0304x over previous
//
#include <hip/hip_runtime.h>
#include <math.h>

#define B_  8
#define N_  128
#define T_  256
#define L_  32
#define H_  128
#define TT_ 224   // T - L

typedef float f2    __attribute__((ext_vector_type(2)));
typedef float f4    __attribute__((ext_vector_type(4)));
typedef float f32x4 __attribute__((ext_vector_type(4)));
typedef short bf16x8 __attribute__((ext_vector_type(8)));

#define L2E_  1.4426950408889634f
#define L2E2_ 2.8853900817779268f

__device__ __forceinline__ unsigned pk2bf(float a, float b) {   // RNE bf16 pack
    unsigned ua = __float_as_uint(a), ub = __float_as_uint(b);
    ua = (ua + 0x7FFFu + ((ua >> 16) & 1u)) >> 16;
    ub = (ub + 0x7FFFu + ((ub >> 16) & 1u)) >> 16;
    return ua | (ub << 16);
}
__device__ __forceinline__ float aexp2(float x) {
    float r; asm("v_exp_f32 %0, %1" : "=v"(r) : "v"(x)); return r;
}
__device__ __forceinline__ float aexp2n(float x) {
    float r; asm("v_exp_f32 %0, -%1" : "=v"(r) : "v"(x)); return r;
}
__device__ __forceinline__ float arcp(float x) {
    return __builtin_amdgcn_rcpf(x);
}

// ---------------------------------------------------------------------------
// R15 = R12 with the tile loop ROLLED (+1-deep register prefetch).
// Seven falsified levers (occupancy R5, VGPR budget R6, W-traffic R7, writes
// R8, DS-ops R12, f32x4-ILP R13 [spilled], f2-ILP R14) all left k_main at
// ~42us. The one invariant across all rounds: a fully-unrolled straight-line
// body where each tile's {ds_read(120cy) -> MFMA -> ~70-op chain -> shuffles}
// runs serially (no regs to pipeline at the 64-VGPR wall) and ~3000 cold
// I-cache instructions execute exactly once per wave. R15 makes the body a
// ~110-inst hot loop and overlaps tile t+1's LDS read with tile t's
// activation via explicit register prefetch (afn/xrn, +5 VGPR).
// Numerics identical to R12. HARD CONSTRAINT (R2/R3/R9, 3/3 NaN): bias
// NEVER via MFMA C-operand; explicit add after MFMA (C = zero4).
// ---------------------------------------------------------------------------
__global__ __launch_bounds__(512, 4)
void k_main(const float* __restrict__ x,
            const float* __restrict__ W_ih,
            const float* __restrict__ b_ih, const float* __restrict__ b_hh,
            const float* __restrict__ W_fc, const float* __restrict__ b_fc,
            float* __restrict__ G, float* __restrict__ xhat) {
    const int n   = blockIdx.x;
    const int y   = blockIdx.y;        // batch pair
    const int b0  = 2 * y;
    const int tid = threadIdx.x;
    const int w    = tid >> 6;    // wave 0..7  == ht
    const int lane = tid & 63;
    const int col  = lane & 15;   // MFMA n index -> t_local
    const int quad = lane >> 4;   // MFMA k-group / row-group

    __shared__ __attribute__((aligned(16))) float xs[2][260];
    __shared__ __attribute__((aligned(16))) unsigned xeo[2][2][128];
    __shared__ __attribute__((aligned(16))) float xr[2][TT_];
    __shared__ uint4 xA[2 * 14 * 64];                  // 28 KB frag table
    __shared__ __attribute__((aligned(16))) float xh_part[2][8][TT_];
    __shared__ __attribute__((aligned(16))) float hd_loc[2][H_];
    __shared__ float red[8];
    __shared__ f4 ws4[32];             // wsum, 16B-aligned
    __shared__ float bp[2];
    __shared__ float bs_s;

    // wsum partials overlay the xA region (wpart live phases A-B; xA built
    // in phase C after the barrier ending wpart's last read). R5-proven.
    f4* wpart = (f4*)xA;

    // ---- phase A: all global reads (W-side paid once for both batches) ----
    union { uint4 u; bf16x8 v; } bfr[3];
    f32x4 biaR[3];
    {
        const int ht = w;
        const int hb = ht * 16 + quad * 4;   // h-base of this lane's 4 rows
        #pragma unroll
        for (int g = 0; g < 3; ++g) {
            const int r  = g * 128 + ht * 16 + col;
            const int sr = r + (r >= 128 ? 128 : 0);
            const float sc = (g == 1) ? L2E2_ : L2E_;
            const f4* src = (const f4*)(W_ih + (size_t)n * 512 * L_ +
                                        (size_t)sr * L_ + quad * 8);
            f4 v0 = src[0] * sc, v1 = src[1] * sc;
            bfr[g].u.x = pk2bf(v0.x, v0.y);
            bfr[g].u.y = pk2bf(v0.z, v0.w);
            bfr[g].u.z = pk2bf(v1.x, v1.y);
            bfr[g].u.w = pk2bf(v1.z, v1.w);
            const int sg = (g == 0) ? 0 : (g == 1 ? 256 : 384);
            const f4 bi = *(const f4*)&b_ih[(size_t)n * 512 + sg + hb];
            const f4 bh = *(const f4*)&b_hh[(size_t)n * 512 + sg + hb];
            const f4 bs = (bi + bh) * sc;
            biaR[g][0] = bs.x; biaR[g][1] = bs.y;
            biaR[g][2] = bs.z; biaR[g][3] = bs.w;
        }
    }
    {   // wsum partials: thread (jg=tid>>5 in 0..15, h4=tid&31) sums 8 j
        const int h4 = tid & 31, jg = tid >> 5;
        const f4* Wf = (const f4*)(W_fc + (size_t)n * N_ * H_) +
                       (size_t)jg * 8 * 32 + h4;
        f4 s = {0.f, 0.f, 0.f, 0.f};
        #pragma unroll
        for (int j = 0; j < 8; ++j) s += Wf[j * 32];
        wpart[jg * 32 + h4] = s;
    }
    if (tid < 128) {   // bsum partials
        float bv = b_fc[n * N_ + tid];
        #pragma unroll
        for (int off = 32; off > 0; off >>= 1) bv += __shfl_down(bv, off, 64);
        if ((tid & 63) == 0) bp[tid >> 6] = bv;
    }
    // stage x for both batches
    if (tid < 256) xs[0][tid] = x[((size_t)b0 * N_ + n) * T_ + tid];
    else           xs[1][tid - 256] = x[((size_t)(b0 + 1) * N_ + n) * T_ + (tid - 256)];
    if (tid < 4) { xs[0][256 + tid] = 0.f; xs[1][256 + tid] = 0.f; }
    __syncthreads();

    // ---- phase B: derived from staged data ----
    if (tid < TT_)                          xr[0][tid]       = 1.0f / xs[0][L_ + tid];
    else if (tid >= 256 && tid < 256 + TT_) xr[1][tid - 256] = 1.0f / xs[1][L_ + tid - 256];
    if (tid < 128) {
        xeo[0][0][tid] = pk2bf(xs[0][2 * tid],     xs[0][2 * tid + 1]);
        xeo[0][1][tid] = pk2bf(xs[0][2 * tid + 1], xs[0][2 * tid + 2]);
    } else if (tid >= 256 && tid < 384) {
        const int t2 = tid - 256;
        xeo[1][0][t2] = pk2bf(xs[1][2 * t2],     xs[1][2 * t2 + 1]);
        xeo[1][1][t2] = pk2bf(xs[1][2 * t2 + 1], xs[1][2 * t2 + 2]);
    }
    if (tid < 32) {   // wsum reduce across 16 jg partials
        f4 s = wpart[tid];
        #pragma unroll
        for (int jg = 1; jg < 16; ++jg) s += wpart[jg * 32 + tid];
        ws4[tid] = s;
    }
    if (tid == 0) bs_s = bp[0] + bp[1];
    __syncthreads();          // wpart's last read done; xA region now free

    // ---- phase C: build per-lane frag table for BOTH batches ----
    for (int e = tid; e < 2 * 14 * 64; e += 512) {
        const int bb = e / 896;
        const int r  = e - bb * 896;
        const int tt = r >> 6, ln = r & 63;
        const int s  = tt * 16 + (ln & 15) + (ln >> 4) * 8;
        const int p  = s & 1, base = s >> 1;
        uint4 v;
        v.x = xeo[bb][p][base + 0]; v.y = xeo[bb][p][base + 1];
        v.z = xeo[bb][p][base + 2]; v.w = xeo[bb][p][base + 3];
        xA[e] = v;
    }
    __syncthreads();

    // wsum for this lane's 4 output rows
    const f4 wshF = ws4[(w * 16 + quad * 4) >> 2];
    const float bsum_n = bs_s;

    const f32x4 zero4 = {0.f, 0.f, 0.f, 0.f};

    // ---- main: ROLLED tile loop with 1-deep register prefetch ----
    #pragma unroll
    for (int bb = 0; bb < 2; ++bb) {
        f32x4 hdacc = {0.f, 0.f, 0.f, 0.f};
        union { uint4 u; bf16x8 v; } afc, afn;
        afc.u = xA[bb * 14 * 64 + lane];
        float xrc = xr[bb][col];
        #pragma unroll 1
        for (int ttile = 0; ttile < 14; ++ttile) {
            // prefetch tile t+1 (index clamped; value unused on last iter)
            const int nidx = (bb * 14 + ttile + 1 < 28) ? (bb * 14 + ttile + 1)
                                                        : 27;
            afn.u = xA[nidx * 64 + lane];
            const float xrn = xr[bb][((ttile + 1) & 15) * 16 + col];

            // swapped operands: A = W-frag (m=h_sub), B = x-frag (n=t), C = 0
            f32x4 gi = __builtin_amdgcn_mfma_f32_16x16x32_bf16(bfr[0].v, afc.v, zero4, 0, 0, 0);
            f32x4 gg = __builtin_amdgcn_mfma_f32_16x16x32_bf16(bfr[1].v, afc.v, zero4, 0, 0, 0);
            f32x4 go = __builtin_amdgcn_mfma_f32_16x16x32_bf16(bfr[2].v, afc.v, zero4, 0, 0, 0);
            gi += biaR[0];                      // explicit per-row bias add
            gg += biaR[1];                      // (NEVER via the C operand)
            go += biaR[2];

            f32x4 e1, e2, e3;
            #pragma unroll
            for (int r = 0; r < 4; ++r) {
                e1[r] = aexp2n(gi[r]);          // e^-gi
                e2[r] = aexp2(gg[r]);           // e^2gg
                e3[r] = aexp2n(go[r]);          // e^-go
            }
            const f32x4 A  = (1.f + e1) * (e2 + 1.f);
            const f32x4 Bv = 1.f + e3;
            const f32x4 AB = A * Bv;
            f32x4 R;
            #pragma unroll
            for (int r = 0; r < 4; ++r) R[r] = arcp(AB[r]);
            const f32x4 em = e2 - 1.f;
            const f32x4 t  = em * R;
            const f32x4 c  = t * Bv;            // sig(gi)*tanh(gg)
            const f32x4 c2 = c * c;
            f32x4 Q = c2 * -0.027698f + 0.120833f;
            Q = c2 * Q - 0.331541f;
            Q = c2 * Q + 1.0f;
            const f32x4 hh = t * Q;             // sig(go)*tanh(c)

            hdacc += hh * xrc;                  // hd partial (t-sum in-lane)
            float xsum = fmaf(hh[0], wshF.x,
                         fmaf(hh[1], wshF.y,
                         fmaf(hh[2], wshF.z,
                         fmaf(hh[3], wshF.w, 0.f))));
            // X_hat partial for t = ttile*16+col: sum over quads
            xsum += __shfl_xor(xsum, 16, 64);
            xsum += __shfl_xor(xsum, 32, 64);
            if (lane < 16) xh_part[bb][w][ttile * 16 + lane] = xsum;

            afc = afn;                          // rotate prefetch
            xrc = xrn;
        }
        // Hd -> LDS: cross-col reduce (per batch)
        #pragma unroll
        for (int r = 0; r < 4; ++r) {
            float v = hdacc[r];
            v += __shfl_xor(v, 1, 64);
            v += __shfl_xor(v, 2, 64);
            v += __shfl_xor(v, 4, 64);
            v += __shfl_xor(v, 8, 64);
            if (col == 0) hd_loc[bb][w * 16 + quad * 4 + r] = v;
        }
    }

    // ---- Dinv partials: waves 0-3 -> batch0, waves 4-7 -> batch1 ----
    {
        const int bb = w >> 2;
        const int t2 = tid - bb * 256;
        float dv = (t2 < TT_) ? xr[bb][t2] : 0.f;
        #pragma unroll
        for (int off = 32; off > 0; off >>= 1) dv += __shfl_down(dv, off, 64);
        if (lane == 0) red[w] = dv;
    }
    __syncthreads();

    // ---- X_hat writeout (both batches) ----
    {
        const int bb = tid >> 8;
        const int tt = tid & 255;
        if (tt < TT_) {
            const float v = (xh_part[bb][0][tt] + xh_part[bb][1][tt]) +
                            (xh_part[bb][2][tt] + xh_part[bb][3][tt]) +
                            (xh_part[bb][4][tt] + xh_part[bb][5][tt]) +
                            (xh_part[bb][6][tt] + xh_part[bb][7][tt]);
            xhat[((size_t)(b0 + bb) * TT_ + tt) * N_ + n] = v + bsum_n + 1e-6f;
        }
    }

    // ---- fused G epilogue: W_fc read once, used for both batches ----
    {
        const float dinv0 = (red[0] + red[1]) + (red[2] + red[3]);
        const float dinv1 = (red[4] + red[5]) + (red[6] + red[7]);
        const int j   = tid >> 2;
        const int qtr = tid & 3;
        const f4* Wf = (const f4*)(W_fc + ((size_t)n * N_ + j) * H_ + qtr * 32);
        float s0 = 0.f, s1 = 0.f;
        #pragma unroll
        for (int q = 0; q < 8; ++q) {
            const f4 wv = Wf[q];
            const int hb = qtr * 32 + q * 4;
            s0 = fmaf(wv.x, hd_loc[0][hb + 0],
                 fmaf(wv.y, hd_loc[0][hb + 1],
                 fmaf(wv.z, hd_loc[0][hb + 2],
                 fmaf(wv.w, hd_loc[0][hb + 3], s0))));
            s1 = fmaf(wv.x, hd_loc[1][hb + 0],
                 fmaf(wv.y, hd_loc[1][hb + 1],
                 fmaf(wv.z, hd_loc[1][hb + 2],
                 fmaf(wv.w, hd_loc[1][hb + 3], s1))));
        }
        s0 += __shfl_xor(s0, 1, 64);
        s0 += __shfl_xor(s0, 2, 64);
        s1 += __shfl_xor(s1, 1, 64);
        s1 += __shfl_xor(s1, 2, 64);
        if (qtr == 0) {
            const float bj = b_fc[n * N_ + j];
            G[(size_t)b0 * N_ * N_ + (size_t)j * N_ + n] =
                (s0 + bj * dinv0) * (1.0f / 224.0f);
            G[(size_t)(b0 + 1) * N_ * N_ + (size_t)j * N_ + n] =
                (s1 + bj * dinv1) * (1.0f / 224.0f);
        }
    }
}

// ---------------------------------------------------------------------------
extern "C" void kernel_launch(void* const* d_in, const int* in_sizes, int n_in,
                              void* d_out, int out_size, void* d_ws, size_t ws_size,
                              hipStream_t stream) {
    const float* x    = (const float*)d_in[0];
    const float* W_ih = (const float*)d_in[1];
    const float* b_ih = (const float*)d_in[2];
    const float* b_hh = (const float*)d_in[3];
    const float* W_fc = (const float*)d_in[4];
    const float* b_fc = (const float*)d_in[5];

    float* G    = (float*)d_out;                        // B*N*N = 131072
    float* xhat = (float*)d_out + (size_t)B_ * N_ * N_; // B*TT*N = 229376

    (void)d_ws; (void)ws_size;   // workspace unused

    k_main<<<dim3(N_, B_ / 2), dim3(512), 0, stream>>>(x, W_ih, b_ih, b_hh,
                                                       W_fc, b_fc, G, xhat);
}